// Round 1
// baseline (209.929 us; speedup 1.0000x reference)
//
#include <hip/hip_runtime.h>
#include <hip/hip_bf16.h>

#define DIM 1024
#define NHEADS 16
#define HD 64
#define BB 2
#define SS 2048
#define MTOT (BB*SS)      // 4096
#define SCALE 0.125f      // HD^-0.5

typedef __attribute__((ext_vector_type(8))) short bf16x8;   // 8 bf16 = 4 VGPRs
typedef __attribute__((ext_vector_type(4))) float f32x4;

__device__ __forceinline__ float bf2f(short u) {
  union { float f; unsigned int i; } v;
  v.i = ((unsigned int)(unsigned short)u) << 16;
  return v.f;
}
__device__ __forceinline__ short f2bf(float f) {
  union { float f; unsigned int i; } v; v.f = f;
  unsigned int r = v.i + 0x7fffu + ((v.i >> 16) & 1u);   // RNE
  return (short)(r >> 16);
}

// ---------------- fp32 -> bf16 ----------------
__global__ void cvt_kernel(const float* __restrict__ in, short* __restrict__ out, int n) {
  int nq = n >> 2;
  int stride = gridDim.x * blockDim.x;
  for (int q = blockIdx.x * blockDim.x + threadIdx.x; q < nq; q += stride) {
    float4 v = *(const float4*)(in + (size_t)q * 4);
    short4 o;
    o.x = f2bf(v.x); o.y = f2bf(v.y); o.z = f2bf(v.z); o.w = f2bf(v.w);
    *(short4*)(out + (size_t)q * 4) = o;
  }
}

// ---------------- RoPE cos/sin table (S x 32, fp32) ----------------
__global__ void rope_table_kernel(float* __restrict__ ct, float* __restrict__ st) {
  int i = blockIdx.x * blockDim.x + threadIdx.x;
  if (i >= SS * 32) return;
  int s = i >> 5, j = i & 31;
  float inv = 1.0f / powf(10000.0f, (float)(2 * j) / 64.0f);
  float ang = (float)s * inv;
  ct[i] = cosf(ang);
  st[i] = sinf(ang);
}

// ---------------- GEMM: C[m][n] = sum_k A[m][k] * B[n][k]  (both row-major, K-contig) ----------------
// 128x128 tile, 4 waves (2x2), BK=32, one mfma_f32_16x16x32_bf16 per 16x16 frag per K-step.
template<bool OUT_F32>
__global__ __launch_bounds__(256) void gemm_bt(
    const short* __restrict__ A, const short* __restrict__ B,
    void* __restrict__ C, int M, int N, int K) {
  __shared__ short As[128][40];   // +8 pad: frag reads ~2-way (free, m136)
  __shared__ short Bs[128][40];
  const int tid = threadIdx.x;
  const int lane = tid & 63;
  const int wid = tid >> 6;
  const int wm = (wid >> 1) * 64, wn = (wid & 1) * 64;
  const int m0 = blockIdx.y * 128, n0 = blockIdx.x * 128;
  const int row = lane & 15, kg = (lane >> 4) * 8;

  f32x4 acc[4][4];
#pragma unroll
  for (int m = 0; m < 4; m++)
#pragma unroll
    for (int n = 0; n < 4; n++) acc[m][n] = (f32x4){0.f, 0.f, 0.f, 0.f};

  const int r0 = tid >> 2;            // 0..63
  const int c0 = (tid & 3) * 8;       // 0,8,16,24
  for (int kk = 0; kk < K; kk += 32) {
    __syncthreads();
    bf16x8 a0 = *(const bf16x8*)(A + (size_t)(m0 + r0) * K + kk + c0);
    bf16x8 a1 = *(const bf16x8*)(A + (size_t)(m0 + 64 + r0) * K + kk + c0);
    bf16x8 b0 = *(const bf16x8*)(B + (size_t)(n0 + r0) * K + kk + c0);
    bf16x8 b1 = *(const bf16x8*)(B + (size_t)(n0 + 64 + r0) * K + kk + c0);
    *(bf16x8*)(&As[r0][c0]) = a0;
    *(bf16x8*)(&As[64 + r0][c0]) = a1;
    *(bf16x8*)(&Bs[r0][c0]) = b0;
    *(bf16x8*)(&Bs[64 + r0][c0]) = b1;
    __syncthreads();
    bf16x8 af[4], bfr[4];
#pragma unroll
    for (int m = 0; m < 4; m++) af[m] = *(const bf16x8*)(&As[wm + m * 16 + row][kg]);
#pragma unroll
    for (int n = 0; n < 4; n++) bfr[n] = *(const bf16x8*)(&Bs[wn + n * 16 + row][kg]);
#pragma unroll
    for (int m = 0; m < 4; m++)
#pragma unroll
      for (int n = 0; n < 4; n++)
        acc[m][n] = __builtin_amdgcn_mfma_f32_16x16x32_bf16(af[m], bfr[n], acc[m][n], 0, 0, 0);
  }
  // epilogue: C/D layout col=lane&15, row=(lane>>4)*4+reg  [m89 verified]
  const int orow = (lane >> 4) * 4, ocol = lane & 15;
#pragma unroll
  for (int m = 0; m < 4; m++)
#pragma unroll
    for (int n = 0; n < 4; n++)
#pragma unroll
      for (int r = 0; r < 4; r++) {
        int gr = m0 + wm + m * 16 + orow + r;
        int gc = n0 + wn + n * 16 + ocol;
        if (OUT_F32) ((float*)C)[(size_t)gr * N + gc] = acc[m][n][r];
        else         ((short*)C)[(size_t)gr * N + gc] = f2bf(acc[m][n][r]);
      }
}

// ---------------- RoPE on Q,K + layout (B,S,3,H,hd) -> (BH,S,hd) ----------------
__global__ __launch_bounds__(256) void rope_kernel(
    const short* __restrict__ qkv, const float* __restrict__ ct, const float* __restrict__ st,
    short* __restrict__ Q, short* __restrict__ K) {
  int bh = blockIdx.y;                  // b*16+h
  int b = bh >> 4, h = bh & 15;
  int s0 = blockIdx.x * 64;
  int t = threadIdx.x;
  int rl = t >> 2;                      // 0..63 row within tile
  int d8 = (t & 3) * 8;                 // 0,8,16,24 (first half)
  int s = s0 + rl;
  size_t inbase = ((size_t)(b * SS + s)) * 3072 + h * 64 + d8;
  size_t outbase = ((size_t)bh * SS + s) * 64 + d8;
  float c[8], sn[8];
#pragma unroll
  for (int j = 0; j < 8; j++) { c[j] = ct[s * 32 + d8 + j]; sn[j] = st[s * 32 + d8 + j]; }
  // Q
  {
    bf16x8 x1 = *(const bf16x8*)(qkv + inbase);
    bf16x8 x2 = *(const bf16x8*)(qkv + inbase + 32);
    bf16x8 o1, o2;
#pragma unroll
    for (int j = 0; j < 8; j++) {
      float a = bf2f(x1[j]), bb = bf2f(x2[j]);
      o1[j] = f2bf(a * c[j] - bb * sn[j]);
      o2[j] = f2bf(bb * c[j] + a * sn[j]);
    }
    *(bf16x8*)(Q + outbase) = o1;
    *(bf16x8*)(Q + outbase + 32) = o2;
  }
  // K
  {
    bf16x8 x1 = *(const bf16x8*)(qkv + inbase + 1024);
    bf16x8 x2 = *(const bf16x8*)(qkv + inbase + 1024 + 32);
    bf16x8 o1, o2;
#pragma unroll
    for (int j = 0; j < 8; j++) {
      float a = bf2f(x1[j]), bb = bf2f(x2[j]);
      o1[j] = f2bf(a * c[j] - bb * sn[j]);
      o2[j] = f2bf(bb * c[j] + a * sn[j]);
    }
    *(bf16x8*)(K + outbase) = o1;
    *(bf16x8*)(K + outbase + 32) = o2;
  }
}

// ---------------- V: (B,S,3,H,hd) -> Vt (BH, hd, S) via LDS transpose ----------------
__global__ __launch_bounds__(256) void vtrans_kernel(const short* __restrict__ qkv, short* __restrict__ Vt) {
  __shared__ short ls[64][72];
  int bh = blockIdx.y, b = bh >> 4, h = bh & 15;
  int s0 = blockIdx.x * 64;
  int t = threadIdx.x;
#pragma unroll
  for (int p = 0; p < 2; p++) {
    int idx = p * 256 + t;
    int r = idx >> 3, c8 = (idx & 7) * 8;
    *(bf16x8*)(&ls[r][c8]) =
        *(const bf16x8*)(qkv + ((size_t)(b * SS + s0 + r)) * 3072 + 2048 + h * 64 + c8);
  }
  __syncthreads();
  int dl = t >> 2, sg = (t & 3) * 16;
  short tmp[16];
#pragma unroll
  for (int j = 0; j < 16; j++) tmp[j] = ls[sg + j][dl];
  *(bf16x8*)(Vt + ((size_t)bh * 64 + dl) * SS + s0 + sg)     = *(bf16x8*)(tmp);
  *(bf16x8*)(Vt + ((size_t)bh * 64 + dl) * SS + s0 + sg + 8) = *(bf16x8*)(tmp + 8);
}

// ---------------- Flash attention, causal. Block: 4 waves x 16 q-rows, KVBLK=64 ----------------
__global__ __launch_bounds__(256) void attn_kernel(
    const short* __restrict__ Q, const short* __restrict__ K, const short* __restrict__ Vt,
    short* __restrict__ O) {
  __shared__ short Ks[64][72];        // [kv][d]
  __shared__ short Vs[64][72];        // [d][kv]  (Vt tile)
  __shared__ short Ps[4][16][72];     // per-wave P [q][kv]
  int qt = (gridDim.x - 1) - blockIdx.x;   // heavy blocks first
  int bh = blockIdx.y;
  int b = bh >> 4, h = bh & 15;
  int q0 = qt * 64;
  int tid = threadIdx.x, lane = tid & 63, w = tid >> 6;
  int row = lane & 15, grp = lane >> 4;

  // Q fragments straight from global (d-contiguous)
  bf16x8 qf[2];
  {
    size_t qbase = ((size_t)bh * SS + q0 + w * 16 + row) * 64 + grp * 8;
    qf[0] = *(const bf16x8*)(Q + qbase);
    qf[1] = *(const bf16x8*)(Q + qbase + 32);
  }
  f32x4 acc[4];
#pragma unroll
  for (int d = 0; d < 4; d++) acc[d] = (f32x4){0.f, 0.f, 0.f, 0.f};
  float mrow[4] = {-1e30f, -1e30f, -1e30f, -1e30f};
  float lrow[4] = {0.f, 0.f, 0.f, 0.f};

  const int r0 = tid >> 3;            // 0..31
  const int c0 = (tid & 7) * 8;       // 0..56
  for (int kt = 0; kt <= qt; kt++) {
    int kv0 = kt * 64;
    __syncthreads();
#pragma unroll
    for (int p = 0; p < 2; p++) {
      int r = p * 32 + r0;
      *(bf16x8*)(&Ks[r][c0]) = *(const bf16x8*)(K + ((size_t)bh * SS + kv0 + r) * 64 + c0);
      *(bf16x8*)(&Vs[r][c0]) = *(const bf16x8*)(Vt + ((size_t)bh * 64 + r) * SS + kv0 + c0);
    }
    __syncthreads();
    // QK^T: A=Q(16q x 32d), B=K^T -> frag from Ks rows (kv = lane&15)
    f32x4 sf[4];
#pragma unroll
    for (int n = 0; n < 4; n++) sf[n] = (f32x4){0.f, 0.f, 0.f, 0.f};
#pragma unroll
    for (int n = 0; n < 4; n++) {
      bf16x8 kf0 = *(const bf16x8*)(&Ks[n * 16 + row][grp * 8]);
      bf16x8 kf1 = *(const bf16x8*)(&Ks[n * 16 + row][grp * 8 + 32]);
      sf[n] = __builtin_amdgcn_mfma_f32_16x16x32_bf16(qf[0], kf0, sf[n], 0, 0, 0);
      sf[n] = __builtin_amdgcn_mfma_f32_16x16x32_bf16(qf[1], kf1, sf[n], 0, 0, 0);
    }
    // scale + causal mask (only the diagonal tile needs it)
    float sv[4][4];
    int qrow0 = q0 + w * 16 + grp * 4;
    bool last = (kt == qt);
#pragma unroll
    for (int n = 0; n < 4; n++)
#pragma unroll
      for (int r = 0; r < 4; r++) {
        float v = sf[n][r] * SCALE;
        if (last && (kv0 + n * 16 + row > qrow0 + r)) v = -1e30f;
        sv[n][r] = v;
      }
    // row max across 4 frags then across the 16 lanes holding the row
    float rmax[4];
#pragma unroll
    for (int r = 0; r < 4; r++)
      rmax[r] = fmaxf(fmaxf(sv[0][r], sv[1][r]), fmaxf(sv[2][r], sv[3][r]));
#pragma unroll
    for (int off = 1; off < 16; off <<= 1)
#pragma unroll
      for (int r = 0; r < 4; r++) rmax[r] = fmaxf(rmax[r], __shfl_xor(rmax[r], off));
    float resc[4], psum[4] = {0.f, 0.f, 0.f, 0.f};
#pragma unroll
    for (int r = 0; r < 4; r++) {
      float mn = fmaxf(mrow[r], rmax[r]);
      resc[r] = __expf(mrow[r] - mn);
      mrow[r] = mn;
    }
#pragma unroll
    for (int n = 0; n < 4; n++)
#pragma unroll
      for (int r = 0; r < 4; r++) {
        float p = __expf(sv[n][r] - mrow[r]);
        psum[r] += p;
        Ps[w][grp * 4 + r][n * 16 + row] = f2bf(p);
      }
#pragma unroll
    for (int off = 1; off < 16; off <<= 1)
#pragma unroll
      for (int r = 0; r < 4; r++) psum[r] += __shfl_xor(psum[r], off);
#pragma unroll
    for (int r = 0; r < 4; r++) lrow[r] = lrow[r] * resc[r] + psum[r];
#pragma unroll
    for (int d = 0; d < 4; d++)
#pragma unroll
      for (int r = 0; r < 4; r++) acc[d][r] *= resc[r];
    // PV: A=P(16q x 32kv) from Ps, B from Vs rows (d = lane&15); same kv slot-map both sides
    bf16x8 pf0 = *(const bf16x8*)(&Ps[w][row][grp * 8]);
    bf16x8 pf1 = *(const bf16x8*)(&Ps[w][row][grp * 8 + 32]);
#pragma unroll
    for (int d = 0; d < 4; d++) {
      bf16x8 vf0 = *(const bf16x8*)(&Vs[d * 16 + row][grp * 8]);
      bf16x8 vf1 = *(const bf16x8*)(&Vs[d * 16 + row][grp * 8 + 32]);
      acc[d] = __builtin_amdgcn_mfma_f32_16x16x32_bf16(pf0, vf0, acc[d], 0, 0, 0);
      acc[d] = __builtin_amdgcn_mfma_f32_16x16x32_bf16(pf1, vf1, acc[d], 0, 0, 0);
    }
  }
  // epilogue: O is (B,S,DIM) bf16, col = h*64 + d
#pragma unroll
  for (int d = 0; d < 4; d++)
#pragma unroll
    for (int r = 0; r < 4; r++) {
      int qq = q0 + w * 16 + grp * 4 + r;
      float o = acc[d][r] / lrow[r];
      O[((size_t)(b * SS + qq)) * 1024 + h * 64 + d * 16 + row] = f2bf(o);
    }
}

extern "C" void kernel_launch(void* const* d_in, const int* in_sizes, int n_in,
                              void* d_out, int out_size, void* d_ws, size_t ws_size,
                              hipStream_t stream) {
  (void)in_sizes; (void)n_in; (void)out_size; (void)ws_size;
  const float* x     = (const float*)d_in[0];
  const float* w_qkv = (const float*)d_in[1];
  const float* w_out = (const float*)d_in[2];
  float* out = (float*)d_out;

  char* ws = (char*)d_ws;
  size_t off = 0;
  auto alloc = [&](size_t bytes) -> void* {
    void* p = ws + off;
    off += (bytes + 255) & ~(size_t)255;
    return p;
  };
  short* xb    = (short*)alloc((size_t)MTOT * DIM * 2);      // dead after GEMM1
  short* wqkvb = (short*)alloc((size_t)3072 * 1024 * 2);
  short* woutb = (short*)alloc((size_t)1024 * 1024 * 2);
  short* qkvb  = (short*)alloc((size_t)MTOT * 3072 * 2);
  short* Qb    = (short*)alloc((size_t)32 * SS * 64 * 2);
  short* Kb    = (short*)alloc((size_t)32 * SS * 64 * 2);
  short* Vtb   = (short*)alloc((size_t)32 * 64 * SS * 2);
  float* ct    = (float*)alloc((size_t)SS * 32 * 4);
  float* st    = (float*)alloc((size_t)SS * 32 * 4);
  short* attnb = xb;   // reuse: xb's last read is GEMM1, attnb written after (stream-ordered)

  cvt_kernel<<<2048, 256, 0, stream>>>(x, xb, MTOT * DIM);
  cvt_kernel<<<2048, 256, 0, stream>>>(w_qkv, wqkvb, 3072 * 1024);
  cvt_kernel<<<1024, 256, 0, stream>>>(w_out, woutb, 1024 * 1024);
  rope_table_kernel<<<SS * 32 / 256, 256, 0, stream>>>(ct, st);
  gemm_bt<false><<<dim3(3072 / 128, MTOT / 128), 256, 0, stream>>>(xb, wqkvb, qkvb, MTOT, 3072, 1024);
  rope_kernel<<<dim3(SS / 64, 32), 256, 0, stream>>>(qkvb, ct, st, Qb, Kb);
  vtrans_kernel<<<dim3(SS / 64, 32), 256, 0, stream>>>(qkvb, Vtb);
  attn_kernel<<<dim3(SS / 64, 32), 256, 0, stream>>>(Qb, Kb, Vtb, attnb);
  gemm_bt<true><<<dim3(1024 / 128, MTOT / 128), 256, 0, stream>>>(attnb, woutb, out, MTOT, 1024, 1024);
}

// Round 2
// 170.418 us; speedup vs baseline: 1.2319x; 1.2319x over previous
//
#include <hip/hip_runtime.h>
#include <hip/hip_bf16.h>

#define DIM 1024
#define NHEADS 16
#define HD 64
#define BB 2
#define SS 2048
#define MTOT (BB*SS)      // 4096
#define SCALE 0.125f      // HD^-0.5

typedef __attribute__((ext_vector_type(8))) short bf16x8;   // 8 bf16 = 4 VGPRs
typedef __attribute__((ext_vector_type(4))) float f32x4;

__device__ __forceinline__ float bf2f(short u) {
  union { float f; unsigned int i; } v;
  v.i = ((unsigned int)(unsigned short)u) << 16;
  return v.f;
}
__device__ __forceinline__ short f2bf(float f) {
  union { float f; unsigned int i; } v; v.f = f;
  unsigned int r = v.i + 0x7fffu + ((v.i >> 16) & 1u);   // RNE
  return (short)(r >> 16);
}

// ---------------- fp32 -> bf16 ----------------
__global__ void cvt_kernel(const float* __restrict__ in, short* __restrict__ out, int n) {
  int nq = n >> 2;
  int stride = gridDim.x * blockDim.x;
  for (int q = blockIdx.x * blockDim.x + threadIdx.x; q < nq; q += stride) {
    float4 v = *(const float4*)(in + (size_t)q * 4);
    short4 o;
    o.x = f2bf(v.x); o.y = f2bf(v.y); o.z = f2bf(v.z); o.w = f2bf(v.w);
    *(short4*)(out + (size_t)q * 4) = o;
  }
}

// ---------------- RoPE cos/sin table (S x 32, fp32) ----------------
__global__ void rope_table_kernel(float* __restrict__ ct, float* __restrict__ st) {
  int i = blockIdx.x * blockDim.x + threadIdx.x;
  if (i >= SS * 32) return;
  int s = i >> 5, j = i & 31;
  float inv = 1.0f / powf(10000.0f, (float)(2 * j) / 64.0f);
  float ang = (float)s * inv;
  ct[i] = cosf(ang);
  st[i] = sinf(ang);
}

// ---------------- GEMM: C[m][n] = sum_k A[m][k] * B[n][k]  (both row-major, K-contig) ----------------
template<bool OUT_F32>
__global__ __launch_bounds__(256) void gemm_bt(
    const short* __restrict__ A, const short* __restrict__ B,
    void* __restrict__ C, int M, int N, int K) {
  __shared__ short As[128][40];
  __shared__ short Bs[128][40];
  const int tid = threadIdx.x;
  const int lane = tid & 63;
  const int wid = tid >> 6;
  const int wm = (wid >> 1) * 64, wn = (wid & 1) * 64;
  const int m0 = blockIdx.y * 128, n0 = blockIdx.x * 128;
  const int row = lane & 15, kg = (lane >> 4) * 8;

  f32x4 acc[4][4];
#pragma unroll
  for (int m = 0; m < 4; m++)
#pragma unroll
    for (int n = 0; n < 4; n++) acc[m][n] = (f32x4){0.f, 0.f, 0.f, 0.f};

  const int r0 = tid >> 2;
  const int c0 = (tid & 3) * 8;
  for (int kk = 0; kk < K; kk += 32) {
    __syncthreads();
    bf16x8 a0 = *(const bf16x8*)(A + (size_t)(m0 + r0) * K + kk + c0);
    bf16x8 a1 = *(const bf16x8*)(A + (size_t)(m0 + 64 + r0) * K + kk + c0);
    bf16x8 b0 = *(const bf16x8*)(B + (size_t)(n0 + r0) * K + kk + c0);
    bf16x8 b1 = *(const bf16x8*)(B + (size_t)(n0 + 64 + r0) * K + kk + c0);
    *(bf16x8*)(&As[r0][c0]) = a0;
    *(bf16x8*)(&As[64 + r0][c0]) = a1;
    *(bf16x8*)(&Bs[r0][c0]) = b0;
    *(bf16x8*)(&Bs[64 + r0][c0]) = b1;
    __syncthreads();
    bf16x8 af[4], bfr[4];
#pragma unroll
    for (int m = 0; m < 4; m++) af[m] = *(const bf16x8*)(&As[wm + m * 16 + row][kg]);
#pragma unroll
    for (int n = 0; n < 4; n++) bfr[n] = *(const bf16x8*)(&Bs[wn + n * 16 + row][kg]);
#pragma unroll
    for (int m = 0; m < 4; m++)
#pragma unroll
      for (int n = 0; n < 4; n++)
        acc[m][n] = __builtin_amdgcn_mfma_f32_16x16x32_bf16(af[m], bfr[n], acc[m][n], 0, 0, 0);
  }
  const int orow = (lane >> 4) * 4, ocol = lane & 15;
#pragma unroll
  for (int m = 0; m < 4; m++)
#pragma unroll
    for (int n = 0; n < 4; n++)
#pragma unroll
      for (int r = 0; r < 4; r++) {
        int gr = m0 + wm + m * 16 + orow + r;
        int gc = n0 + wn + n * 16 + ocol;
        if (OUT_F32) ((float*)C)[(size_t)gr * N + gc] = acc[m][n][r];
        else         ((short*)C)[(size_t)gr * N + gc] = f2bf(acc[m][n][r]);
      }
}

// ---------------- RoPE on Q,K + layout (B,S,3,H,hd) -> (BH,S,hd) ----------------
__global__ __launch_bounds__(256) void rope_kernel(
    const short* __restrict__ qkv, const float* __restrict__ ct, const float* __restrict__ st,
    short* __restrict__ Q, short* __restrict__ K) {
  int bh = blockIdx.y;
  int b = bh >> 4, h = bh & 15;
  int s0 = blockIdx.x * 64;
  int t = threadIdx.x;
  int rl = t >> 2;
  int d8 = (t & 3) * 8;
  int s = s0 + rl;
  size_t inbase = ((size_t)(b * SS + s)) * 3072 + h * 64 + d8;
  size_t outbase = ((size_t)bh * SS + s) * 64 + d8;
  float c[8], sn[8];
#pragma unroll
  for (int j = 0; j < 8; j++) { c[j] = ct[s * 32 + d8 + j]; sn[j] = st[s * 32 + d8 + j]; }
  {
    bf16x8 x1 = *(const bf16x8*)(qkv + inbase);
    bf16x8 x2 = *(const bf16x8*)(qkv + inbase + 32);
    bf16x8 o1, o2;
#pragma unroll
    for (int j = 0; j < 8; j++) {
      float a = bf2f(x1[j]), bb = bf2f(x2[j]);
      o1[j] = f2bf(a * c[j] - bb * sn[j]);
      o2[j] = f2bf(bb * c[j] + a * sn[j]);
    }
    *(bf16x8*)(Q + outbase) = o1;
    *(bf16x8*)(Q + outbase + 32) = o2;
  }
  {
    bf16x8 x1 = *(const bf16x8*)(qkv + inbase + 1024);
    bf16x8 x2 = *(const bf16x8*)(qkv + inbase + 1024 + 32);
    bf16x8 o1, o2;
#pragma unroll
    for (int j = 0; j < 8; j++) {
      float a = bf2f(x1[j]), bb = bf2f(x2[j]);
      o1[j] = f2bf(a * c[j] - bb * sn[j]);
      o2[j] = f2bf(bb * c[j] + a * sn[j]);
    }
    *(bf16x8*)(K + outbase) = o1;
    *(bf16x8*)(K + outbase + 32) = o2;
  }
}

// ---------------- V: (B,S,3,H,hd) -> Vt (BH, hd, S) via LDS transpose ----------------
__global__ __launch_bounds__(256) void vtrans_kernel(const short* __restrict__ qkv, short* __restrict__ Vt) {
  __shared__ short ls[64][72];
  int bh = blockIdx.y, b = bh >> 4, h = bh & 15;
  int s0 = blockIdx.x * 64;
  int t = threadIdx.x;
#pragma unroll
  for (int p = 0; p < 2; p++) {
    int idx = p * 256 + t;
    int r = idx >> 3, c8 = (idx & 7) * 8;
    *(bf16x8*)(&ls[r][c8]) =
        *(const bf16x8*)(qkv + ((size_t)(b * SS + s0 + r)) * 3072 + 2048 + h * 64 + c8);
  }
  __syncthreads();
  int dl = t >> 2, sg = (t & 3) * 16;
  short tmp[16];
#pragma unroll
  for (int j = 0; j < 16; j++) tmp[j] = ls[sg + j][dl];
  *(bf16x8*)(Vt + ((size_t)bh * 64 + dl) * SS + s0 + sg)     = *(bf16x8*)(tmp);
  *(bf16x8*)(Vt + ((size_t)bh * 64 + dl) * SS + s0 + sg + 8) = *(bf16x8*)(tmp + 8);
}

// ---------------- Flash attention, causal. Swapped-operand, lane-local softmax ----------------
// S^T = mfma(K_frag, Q_frag): C/D layout col=lane&15 -> q, row=grp*4+r -> kv.
// Each lane owns ONE q-row: scalar m/l, 2+2 shfl_xor reduce, P stays in registers.
// PV swapped: O^T = mfma(V^T_frag, P_frag) with matching (grp,slot)->kv bijection
//   k_slot(g,j) = 16*(j>>2) + g*4 + (j&3)   on both A (V^T) and B (P^T) sides.
__global__ __launch_bounds__(256) void attn_kernel(
    const short* __restrict__ Q, const short* __restrict__ K, const short* __restrict__ Vt,
    short* __restrict__ O) {
  __shared__ short Ks[64][72];        // [kv][d]
  __shared__ short Vs[64][72];        // [d][kv]  (Vt tile)
  int flat = blockIdx.x;
  int wk = (flat & 7) * 128 + (flat >> 3);   // XCD-chunked swizzle: 4 bh per XCD (1024%8==0, bijective)
  int bh = wk >> 5;
  int qt = 31 - (wk & 31);                   // heavy q-tiles first within each chunk
  int b = bh >> 4, h = bh & 15;
  int q0 = qt * 64;
  int tid = threadIdx.x, lane = tid & 63, w = tid >> 6;
  int row = lane & 15, grp = lane >> 4;
  int q = q0 + w * 16 + row;                 // this lane's q row

  bf16x8 qf0, qf1;
  {
    size_t qbase = ((size_t)bh * SS + q) * 64 + grp * 8;
    qf0 = *(const bf16x8*)(Q + qbase);
    qf1 = *(const bf16x8*)(Q + qbase + 32);
  }
  f32x4 acc[4];
#pragma unroll
  for (int d = 0; d < 4; d++) acc[d] = (f32x4){0.f, 0.f, 0.f, 0.f};
  float m = -1e30f, l = 0.f;

  const int r0 = tid >> 3;
  const int c0 = (tid & 7) * 8;
  for (int kt = 0; kt <= qt; kt++) {
    int kv0 = kt * 64;
    __syncthreads();
#pragma unroll
    for (int p2 = 0; p2 < 2; p2++) {
      int r = p2 * 32 + r0;
      *(bf16x8*)(&Ks[r][c0]) = *(const bf16x8*)(K + ((size_t)bh * SS + kv0 + r) * 64 + c0);
      *(bf16x8*)(&Vs[r][c0]) = *(const bf16x8*)(Vt + ((size_t)bh * 64 + r) * SS + kv0 + c0);
    }
    __syncthreads();
    bool last = (kt == qt);
    float sv[4][4];
#pragma unroll
    for (int n = 0; n < 4; n++) {
      if (last && n > w) {                 // kv block fully above diagonal for this wave
#pragma unroll
        for (int r = 0; r < 4; r++) sv[n][r] = -1e30f;
        continue;
      }
      f32x4 sf = (f32x4){0.f, 0.f, 0.f, 0.f};
      bf16x8 kf0 = *(const bf16x8*)(&Ks[n * 16 + row][grp * 8]);
      bf16x8 kf1 = *(const bf16x8*)(&Ks[n * 16 + row][grp * 8 + 32]);
      sf = __builtin_amdgcn_mfma_f32_16x16x32_bf16(kf0, qf0, sf, 0, 0, 0);
      sf = __builtin_amdgcn_mfma_f32_16x16x32_bf16(kf1, qf1, sf, 0, 0, 0);
#pragma unroll
      for (int r = 0; r < 4; r++) {
        int kv = kv0 + n * 16 + grp * 4 + r;
        float v = sf[r] * SCALE;
        sv[n][r] = (last && kv > q) ? -1e30f : v;
      }
    }
    // lane-local row max over 16 kv, then 4-lane group reduce (lanes q, q+16, q+32, q+48)
    float pmax = -1e30f;
#pragma unroll
    for (int n = 0; n < 4; n++)
#pragma unroll
      for (int r = 0; r < 4; r++) pmax = fmaxf(pmax, sv[n][r]);
    pmax = fmaxf(pmax, __shfl_xor(pmax, 16));
    pmax = fmaxf(pmax, __shfl_xor(pmax, 32));
    float mn = fmaxf(m, pmax);
    float resc = __expf(m - mn);
    m = mn;
    float p[4][4];
    float psum = 0.f;
#pragma unroll
    for (int n = 0; n < 4; n++)
#pragma unroll
      for (int r = 0; r < 4; r++) {
        p[n][r] = __expf(sv[n][r] - m);
        psum += p[n][r];
      }
    psum += __shfl_xor(psum, 16);
    psum += __shfl_xor(psum, 32);
    l = l * resc + psum;
#pragma unroll
    for (int d = 0; d < 4; d++)
#pragma unroll
      for (int r = 0; r < 4; r++) acc[d][r] *= resc;
    // PV: two K=32 chunks (c), per chunk 4 d-blocks
#pragma unroll
    for (int c = 0; c < 2; c++) {
      bf16x8 pf;
#pragma unroll
      for (int j = 0; j < 4; j++) {
        pf[j]     = f2bf(p[2 * c][j]);       // k_slot j   -> kv = c*32 + g*4 + j
        pf[j + 4] = f2bf(p[2 * c + 1][j]);   // k_slot j+4 -> kv = c*32 + 16 + g*4 + j
      }
#pragma unroll
      for (int dm = 0; dm < 4; dm++) {
        short4 v0 = *(const short4*)(&Vs[dm * 16 + row][c * 32 + grp * 4]);
        short4 v1 = *(const short4*)(&Vs[dm * 16 + row][c * 32 + 16 + grp * 4]);
        bf16x8 vf = {v0.x, v0.y, v0.z, v0.w, v1.x, v1.y, v1.z, v1.w};
        acc[dm] = __builtin_amdgcn_mfma_f32_16x16x32_bf16(vf, pf, acc[dm], 0, 0, 0);
      }
    }
  }
  // epilogue: O^T layout -> lane holds q = q0+w*16+(lane&15), d = dm*16+grp*4+r
  float linv = 1.0f / l;
#pragma unroll
  for (int dm = 0; dm < 4; dm++)
#pragma unroll
    for (int r = 0; r < 4; r++) {
      int d = dm * 16 + grp * 4 + r;
      O[((size_t)(b * SS + q)) * 1024 + h * 64 + d] = f2bf(acc[dm][r] * linv);
    }
}

extern "C" void kernel_launch(void* const* d_in, const int* in_sizes, int n_in,
                              void* d_out, int out_size, void* d_ws, size_t ws_size,
                              hipStream_t stream) {
  (void)in_sizes; (void)n_in; (void)out_size; (void)ws_size;
  const float* x     = (const float*)d_in[0];
  const float* w_qkv = (const float*)d_in[1];
  const float* w_out = (const float*)d_in[2];
  float* out = (float*)d_out;

  char* ws = (char*)d_ws;
  size_t off = 0;
  auto alloc = [&](size_t bytes) -> void* {
    void* p = ws + off;
    off += (bytes + 255) & ~(size_t)255;
    return p;
  };
  short* xb    = (short*)alloc((size_t)MTOT * DIM * 2);      // dead after GEMM1
  short* wqkvb = (short*)alloc((size_t)3072 * 1024 * 2);
  short* woutb = (short*)alloc((size_t)1024 * 1024 * 2);
  short* qkvb  = (short*)alloc((size_t)MTOT * 3072 * 2);
  short* Qb    = (short*)alloc((size_t)32 * SS * 64 * 2);
  short* Kb    = (short*)alloc((size_t)32 * SS * 64 * 2);
  short* Vtb   = (short*)alloc((size_t)32 * 64 * SS * 2);
  float* ct    = (float*)alloc((size_t)SS * 32 * 4);
  float* st    = (float*)alloc((size_t)SS * 32 * 4);
  short* attnb = xb;   // reuse: xb's last read is GEMM1, attnb written after (stream-ordered)

  cvt_kernel<<<2048, 256, 0, stream>>>(x, xb, MTOT * DIM);
  cvt_kernel<<<2048, 256, 0, stream>>>(w_qkv, wqkvb, 3072 * 1024);
  cvt_kernel<<<1024, 256, 0, stream>>>(w_out, woutb, 1024 * 1024);
  rope_table_kernel<<<SS * 32 / 256, 256, 0, stream>>>(ct, st);
  gemm_bt<false><<<dim3(3072 / 128, MTOT / 128), 256, 0, stream>>>(xb, wqkvb, qkvb, MTOT, 3072, 1024);
  rope_kernel<<<dim3(SS / 64, 32), 256, 0, stream>>>(qkvb, ct, st, Qb, Kb);
  vtrans_kernel<<<dim3(SS / 64, 32), 256, 0, stream>>>(qkvb, Vtb);
  attn_kernel<<<1024, 256, 0, stream>>>(Qb, Kb, Vtb, attnb);
  gemm_bt<true><<<dim3(1024 / 128, MTOT / 128), 256, 0, stream>>>(attnb, woutb, out, MTOT, 1024, 1024);
}